// Round 4
// baseline (1486.452 us; speedup 1.0000x reference)
//
#include <hip/hip_runtime.h>
#include <math.h>

#define NNODES 10000
#define NEDGES 50000
#define ND 1152
#define MUL 128
#define WNW 1408
#define EDIM 20

#define CK1 0.5773502691896258f
#define CK2 0.4472135954999579f
#define A2C 0.31622776601683794f
#define A0A (-0.18257418583505536f)
#define A0B 0.3651483716701107f
#define B1C 0.11952286093343936f
#define B2C 0.23904572186687873f
#define B3C 0.20701966780270626f
#define PW0 0.5773502691896258f
#define PW1 0.8660254037844386f
#define PW2 1.1180339887498949f
#define INV128 0.08838834764831845f

__device__ __forceinline__ float silu_f(float v) { return v / (1.f + expf(-v)); }

typedef short bfrag __attribute__((ext_vector_type(8)));   // 8 bf16 (4 VGPR)
typedef float f32x4 __attribute__((ext_vector_type(4)));

__device__ __forceinline__ ushort f2bf(float f) {          // RNE fp32->bf16
    uint u = __float_as_uint(f);
    u += 0x7fffu + ((u >> 16) & 1u);
    return (ushort)(u >> 16);
}
__device__ __forceinline__ float bf2f(ushort h) {
    return __uint_as_float(((uint)h) << 16);
}

#define LSTR 40   // LDS row stride in bf16 (80 B = 20-bank step -> <=2-way)

// ============================================================================
// Unified split-bf16 MFMA GEMM.  C = A @ B (+bias variants).
// A sources (ASRC):
//   0: plain fp32 [M][lda], guarded at Kreal (er1, K padded to 32)
//   1: PRE-SPLIT bf16 H/L pair [M][lda] — staging is pure 16B copies
//   2: s0 edge assembly gather (xs | xd | dots), K=512 (es1)
//   3: strided o3 component from interleaved x rows, z = blockIdx.z (o3pre)
// B is always pre-split/transposed bf16 H/L, [N][K] (K = padded loop K).
// Epilogues (OSINK):
//   0: fp32 C (+SILU opt)
//   1: split bf16 H/L C (+SILU opt)   [producer-side split]
//   2: o3pre plane: C + z*M*ldc, v*INV128 (+bias at z==0)
// DUAL: two GEMMs (A1@B1, A2@B2), C = (r1+b1)*(r2+b2) fp32  [w2fused].
// 128x128 tile, 256 thr = 4 waves (2x2 of 64x64), mfma_f32_16x16x32_bf16,
// 3 products per pair (hi*hi + hi*lo + lo*hi).
// ============================================================================
template<int DUAL, int SILU, int ASRC, int OSINK>
__global__ __launch_bounds__(256) void gemmbf(
    const void* __restrict__ A1p, const void* __restrict__ A1s, int lda,
    const ushort* __restrict__ B1H, const ushort* __restrict__ B1L,
    const float* __restrict__ b1,
    const void* __restrict__ A2p, const void* __restrict__ A2s,
    const ushort* __restrict__ B2H, const ushort* __restrict__ B2L,
    const float* __restrict__ b2,
    const ushort* __restrict__ W2H, const ushort* __restrict__ W2L,
    float* __restrict__ C, ushort* __restrict__ CH, ushort* __restrict__ CL,
    int ldc, int M, int K, int Kreal,
    const float* __restrict__ xg, const int* __restrict__ ei,
    const float* __restrict__ dots)
{
    __shared__ __align__(16) ushort Ah[128 * LSTR];
    __shared__ __align__(16) ushort Al[128 * LSTR];
    __shared__ __align__(16) ushort Bh[128 * LSTR];
    __shared__ __align__(16) ushort Bl[128 * LSTR];

    const int tid = threadIdx.x;
    const int l   = tid & 63;
    const int wid = tid >> 6;
    const int wr  = (wid >> 1) << 6;       // wave row offset (0/64)
    const int wc  = (wid & 1) << 6;        // wave col offset (0/64)
    const int rowBase = blockIdx.y << 7;
    const int n0      = blockIdx.x << 7;

    const int sRow = tid >> 1;             // A staging: row 0..127
    const int sK   = (tid & 1) << 4;       // 0/16 (elements)
    const int bN   = tid & 127;            // B staging: n 0..127
    const int bK   = (tid >> 7) << 4;      // 0/16 (bf16)

    const int frow = l & 15;               // fragment row/col within 16
    const int fk   = (l >> 4) << 3;        // fragment k offset (0,8,16,24)

    // o3pre per-z config
    const int z = (ASRC == 3) ? blockIdx.z : 0;
    int zoff = 0, zstride = 1;
    if constexpr (ASRC == 3) {
        if (z == 0)      { zoff = 0;             zstride = 1; }
        else if (z < 4)  { zoff = 128 + (z - 1); zstride = 3; }
        else             { zoff = 512 + (z - 4); zstride = 5; }
    }

    f32x4 acc0[4][4], acc1[4][4];
#pragma unroll
    for (int m = 0; m < 4; ++m)
#pragma unroll
        for (int n = 0; n < 4; ++n) {
            acc0[m][n] = f32x4{0.f, 0.f, 0.f, 0.f};
            if constexpr (DUAL) acc1[m][n] = f32x4{0.f, 0.f, 0.f, 0.f};
        }

#pragma unroll
    for (int ph = 0; ph < (DUAL ? 2 : 1); ++ph) {
        const void* Ap  = (DUAL && ph) ? A2p : A1p;
        const void* Asp = (DUAL && ph) ? A2s : A1s;
        const ushort* BH = (DUAL && ph) ? B2H : B1H;
        const ushort* BL = (DUAL && ph) ? B2L : B1L;
        if constexpr (ASRC == 3) {        // o3 weight select by l
            if (z >= 1 && z < 4) { BH = B2H; BL = B2L; }
            else if (z >= 4)     { BH = W2H; BL = W2L; }
        }

        for (int k0 = 0; k0 < K; k0 += 32) {
            // ---- stage A ----
            {
                int grow = rowBase + sRow;
                if constexpr (ASRC == 1) {
                    uint4 h0 = {0,0,0,0}, h1v = {0,0,0,0};
                    uint4 l0 = {0,0,0,0}, l1v = {0,0,0,0};
                    if (grow < M) {
                        const ushort* AH = ((const ushort*)Ap)  + (size_t)grow * lda + k0 + sK;
                        const ushort* AL = ((const ushort*)Asp) + (size_t)grow * lda + k0 + sK;
                        h0  = *(const uint4*)AH; h1v = *(const uint4*)(AH + 8);
                        l0  = *(const uint4*)AL; l1v = *(const uint4*)(AL + 8);
                    }
                    int base = sRow * LSTR + sK;
                    *(uint4*)&Ah[base]     = h0;  *(uint4*)&Ah[base + 8] = h1v;
                    *(uint4*)&Al[base]     = l0;  *(uint4*)&Al[base + 8] = l1v;
                } else {
                    float f[16];
                    if (grow < M) {
                        if constexpr (ASRC == 0) {
#pragma unroll
                            for (int j = 0; j < 16; ++j) {
                                int gk = k0 + sK + j;
                                f[j] = (gk < Kreal)
                                     ? ((const float*)Ap)[(size_t)grow * lda + gk] : 0.f;
                            }
                        } else if constexpr (ASRC == 2) {
                            int gk = k0 + sK;
                            const float4* p;
                            if (gk < 128)
                                p = (const float4*)&xg[(size_t)ei[grow] * ND + gk];
                            else if (gk < 256)
                                p = (const float4*)&xg[(size_t)ei[NEDGES + grow] * ND + (gk - 128)];
                            else
                                p = (const float4*)&dots[(size_t)grow * 256 + (gk - 256)];
#pragma unroll
                            for (int j = 0; j < 4; ++j) {
                                float4 v = p[j];
                                f[j*4+0] = v.x; f[j*4+1] = v.y;
                                f[j*4+2] = v.z; f[j*4+3] = v.w;
                            }
                        } else {  // ASRC == 3
                            const float* p = &((const float*)Ap)[(size_t)grow * lda + zoff];
#pragma unroll
                            for (int j = 0; j < 16; ++j)
                                f[j] = p[(k0 + sK + j) * zstride];
                        }
                    } else {
#pragma unroll
                        for (int j = 0; j < 16; ++j) f[j] = 0.f;
                    }
                    int base = sRow * LSTR + sK;
#pragma unroll
                    for (int j = 0; j < 4; ++j) {
                        ushort4 hv, lv;
                        hv.x = f2bf(f[j*4+0]); lv.x = f2bf(f[j*4+0] - bf2f(hv.x));
                        hv.y = f2bf(f[j*4+1]); lv.y = f2bf(f[j*4+1] - bf2f(hv.y));
                        hv.z = f2bf(f[j*4+2]); lv.z = f2bf(f[j*4+2] - bf2f(hv.z));
                        hv.w = f2bf(f[j*4+3]); lv.w = f2bf(f[j*4+3] - bf2f(hv.w));
                        *(ushort4*)&Ah[base + j*4] = hv;
                        *(ushort4*)&Al[base + j*4] = lv;
                    }
                }
            }
            // ---- stage B (pre-split copy) ----
            {
                size_t go = (size_t)(n0 + bN) * K + k0 + bK;
                uint4 h0 = *(const uint4*)&BH[go];
                uint4 h1v = *(const uint4*)&BH[go + 8];
                uint4 l0 = *(const uint4*)&BL[go];
                uint4 l1v = *(const uint4*)&BL[go + 8];
                int bb = bN * LSTR + bK;
                *(uint4*)&Bh[bb]     = h0;
                *(uint4*)&Bh[bb + 8] = h1v;
                *(uint4*)&Bl[bb]     = l0;
                *(uint4*)&Bl[bb + 8] = l1v;
            }
            __syncthreads();
            // ---- fragments + MFMA (3 split products) ----
            bfrag bhF[4], blF[4];
#pragma unroll
            for (int n = 0; n < 4; ++n) {
                int r = (wc + n * 16 + frow) * LSTR + fk;
                bhF[n] = *(const bfrag*)&Bh[r];
                blF[n] = *(const bfrag*)&Bl[r];
            }
#pragma unroll
            for (int m = 0; m < 4; ++m) {
                int r = (wr + m * 16 + frow) * LSTR + fk;
                bfrag ah = *(const bfrag*)&Ah[r];
                bfrag al = *(const bfrag*)&Al[r];
#pragma unroll
                for (int n = 0; n < 4; ++n) {
                    f32x4 a = (DUAL && ph) ? acc1[m][n] : acc0[m][n];
                    a = __builtin_amdgcn_mfma_f32_16x16x32_bf16(ah, bhF[n], a, 0, 0, 0);
                    a = __builtin_amdgcn_mfma_f32_16x16x32_bf16(ah, blF[n], a, 0, 0, 0);
                    a = __builtin_amdgcn_mfma_f32_16x16x32_bf16(al, bhF[n], a, 0, 0, 0);
                    if (DUAL && ph) acc1[m][n] = a; else acc0[m][n] = a;
                }
            }
            __syncthreads();
        }
    }

    // ---- epilogue ----
#pragma unroll
    for (int n = 0; n < 4; ++n) {
        int col = n0 + wc + n * 16 + frow;
        float bb1 = b1 ? b1[col] : 0.f;
        float bb2 = (DUAL && b2) ? b2[col] : 0.f;
#pragma unroll
        for (int m = 0; m < 4; ++m) {
            int row0 = rowBase + wr + m * 16 + ((l >> 4) << 2);
#pragma unroll
            for (int q = 0; q < 4; ++q) {
                int row = row0 + q;
                if (row >= M) continue;
                if constexpr (DUAL) {
                    float v = (acc0[m][n][q] + bb1) * (acc1[m][n][q] + bb2);
                    C[(size_t)row * ldc + col] = v;
                } else if constexpr (OSINK == 0) {
                    float v = acc0[m][n][q] + bb1;
                    if constexpr (SILU) v = silu_f(v);
                    C[(size_t)row * ldc + col] = v;
                } else if constexpr (OSINK == 1) {
                    float v = acc0[m][n][q] + bb1;
                    if constexpr (SILU) v = silu_f(v);
                    ushort h  = f2bf(v);
                    ushort lo = f2bf(v - bf2f(h));
                    CH[(size_t)row * ldc + col] = h;
                    CL[(size_t)row * ldc + col] = lo;
                } else {  // OSINK == 2 : o3pre plane
                    float v = acc0[m][n][q] * INV128;
                    if (z == 0 && b1) v += b1[col];
                    C[(size_t)z * M * ldc + (size_t)row * ldc + col] = v;
                }
            }
        }
    }
}

// ============================================================================
// o3-post multi-plane split-bf16 MFMA (unchanged from r3):
//   out[row, OFF + col*NPL + p] = INV128 * sum_u (fij_p[row,u]*g[row,GOFF+u]) W[u,col]
// ============================================================================
template<int NPL, int OFF, int GOFF>
__global__ __launch_bounds__(256) void o3postbf(
    const float* __restrict__ fij, size_t FP,
    const float* __restrict__ g,
    const ushort* __restrict__ WH, const ushort* __restrict__ WL,
    float* __restrict__ out, int M)
{
    __shared__ __align__(16) ushort Ah[NPL * 32 * LSTR];
    __shared__ __align__(16) ushort Al[NPL * 32 * LSTR];
    __shared__ __align__(16) ushort Bh[128 * LSTR];
    __shared__ __align__(16) ushort Bl[128 * LSTR];

    const int tid = threadIdx.x;
    const int l   = tid & 63;
    const int wid = tid >> 6;
    const int wr  = (wid >> 1) << 4;
    const int wc  = (wid & 1) << 6;
    const int rowBase = blockIdx.x << 5;

    const int sR = tid >> 3;
    const int sK = (tid & 7) << 2;
    const int bN = tid & 127;
    const int bK = (tid >> 7) << 4;

    const int frow = l & 15;
    const int fk   = (l >> 4) << 3;

    f32x4 acc[NPL][4];
#pragma unroll
    for (int p = 0; p < NPL; ++p)
#pragma unroll
        for (int n = 0; n < 4; ++n) acc[p][n] = f32x4{0.f, 0.f, 0.f, 0.f};

    for (int k0 = 0; k0 < 128; k0 += 32) {
        int grow = rowBase + sR;
        float4 g4 = make_float4(0.f, 0.f, 0.f, 0.f);
        if (grow < M)
            g4 = *(const float4*)&g[(size_t)grow * 384 + GOFF + k0 + sK];
#pragma unroll
        for (int p = 0; p < NPL; ++p) {
            float4 v;
            if constexpr (NPL == 1) {
                v = g4;
            } else {
                float4 f4 = make_float4(0.f, 0.f, 0.f, 0.f);
                if (grow < M)
                    f4 = *(const float4*)&fij[(size_t)p * FP + (size_t)grow * 128 + k0 + sK];
                v = make_float4(f4.x * g4.x, f4.y * g4.y, f4.z * g4.z, f4.w * g4.w);
            }
            ushort4 hv, lv;
            hv.x = f2bf(v.x); lv.x = f2bf(v.x - bf2f(hv.x));
            hv.y = f2bf(v.y); lv.y = f2bf(v.y - bf2f(hv.y));
            hv.z = f2bf(v.z); lv.z = f2bf(v.z - bf2f(hv.z));
            hv.w = f2bf(v.w); lv.w = f2bf(v.w - bf2f(hv.w));
            int base = (p * 32 + sR) * LSTR + sK;
            *(ushort4*)&Ah[base] = hv;
            *(ushort4*)&Al[base] = lv;
        }
        {
            size_t go = (size_t)bN * 128 + k0 + bK;
            uint4 h0 = *(const uint4*)&WH[go];
            uint4 h1 = *(const uint4*)&WH[go + 8];
            uint4 l0 = *(const uint4*)&WL[go];
            uint4 l1 = *(const uint4*)&WL[go + 8];
            int bb = bN * LSTR + bK;
            *(uint4*)&Bh[bb]     = h0;
            *(uint4*)&Bh[bb + 8] = h1;
            *(uint4*)&Bl[bb]     = l0;
            *(uint4*)&Bl[bb + 8] = l1;
        }
        __syncthreads();
        bfrag bhF[4], blF[4];
#pragma unroll
        for (int n = 0; n < 4; ++n) {
            int r = (wc + n * 16 + frow) * LSTR + fk;
            bhF[n] = *(const bfrag*)&Bh[r];
            blF[n] = *(const bfrag*)&Bl[r];
        }
#pragma unroll
        for (int p = 0; p < NPL; ++p) {
            int r = (p * 32 + wr + frow) * LSTR + fk;
            bfrag ah = *(const bfrag*)&Ah[r];
            bfrag al = *(const bfrag*)&Al[r];
#pragma unroll
            for (int n = 0; n < 4; ++n) {
                acc[p][n] = __builtin_amdgcn_mfma_f32_16x16x32_bf16(ah, bhF[n], acc[p][n], 0, 0, 0);
                acc[p][n] = __builtin_amdgcn_mfma_f32_16x16x32_bf16(ah, blF[n], acc[p][n], 0, 0, 0);
                acc[p][n] = __builtin_amdgcn_mfma_f32_16x16x32_bf16(al, bhF[n], acc[p][n], 0, 0, 0);
            }
        }
        __syncthreads();
    }

#pragma unroll
    for (int n = 0; n < 4; ++n) {
        int col = wc + n * 16 + frow;
#pragma unroll
        for (int q = 0; q < 4; ++q) {
            int row = rowBase + wr + ((l >> 4) << 2) + q;
            if (row >= M) continue;
            float* po = &out[(size_t)row * ND + OFF + col * NPL];
#pragma unroll
            for (int p = 0; p < NPL; ++p)
                po[p] = acc[p][n][q] * INV128;
        }
    }
}

// ============================================================================
// One-time weight split+transpose: W[K][N] fp32 -> H/L [N][Kp] bf16 (zero-pad
// k in [K, Kp)). grid.y selects matrix; out is one packed ushort arena.
// ============================================================================
__global__ void wsplit_kernel(
    const float* __restrict__ W0,  const float* __restrict__ W1,
    const float* __restrict__ W2,  const float* __restrict__ W3,
    const float* __restrict__ W4,  const float* __restrict__ W5,
    const float* __restrict__ W6,  const float* __restrict__ W7,
    const float* __restrict__ W8,  const float* __restrict__ W9,
    const float* __restrict__ W10, const float* __restrict__ W11,
    const float* __restrict__ W12, const float* __restrict__ W13,
    ushort* __restrict__ out)
{
    int m = blockIdx.y;
    const float* W; int K, Kp, N; size_t off;
    switch (m) {
        case 0:  W = W0;  K = 128; Kp = 128; N = 1408; off = 0;       break;
        case 1:  W = W1;  K = 128; Kp = 128; N = 1408; off = 360448;  break;
        case 2:  W = W2;  K = 384; Kp = 384; N = 384;  off = 720896;  break;
        case 3:  W = W3;  K = 384; Kp = 384; N = 384;  off = 1015808; break;
        case 4:  W = W4;  K = 384; Kp = 384; N = 384;  off = 1310720; break;
        case 5:  W = W5;  K = 384; Kp = 384; N = 384;  off = 1605632; break;
        case 6:  W = W6;  K = 128; Kp = 128; N = 128;  off = 1900544; break;
        case 7:  W = W7;  K = 128; Kp = 128; N = 128;  off = 1933312; break;
        case 8:  W = W8;  K = 128; Kp = 128; N = 128;  off = 1966080; break;
        case 9:  W = W9;  K = 128; Kp = 128; N = 128;  off = 1998848; break;
        case 10: W = W10; K = 128; Kp = 128; N = 128;  off = 2031616; break;
        case 11: W = W11; K = 128; Kp = 128; N = 128;  off = 2064384; break;
        case 12: W = W12; K = 512; Kp = 512; N = 128;  off = 2097152; break;
        default: W = W13; K = 20;  Kp = 32;  N = 128;  off = 2228224; break;
    }
    int idx = blockIdx.x * 256 + threadIdx.x;
    if (idx >= Kp * N) return;
    int k = idx / N, n = idx - k * N;
    float v = (k < K) ? W[(size_t)k * N + n] : 0.f;
    ushort h  = f2bf(v);
    ushort lo = f2bf(v - bf2f(h));
    size_t KN = (size_t)Kp * N;
    out[off + (size_t)n * Kp + k]      = h;
    out[off + KN + (size_t)n * Kp + k] = lo;
}

// ============================================================================
// dots for s0 (reads interleaved input x)
// ============================================================================
__global__ void dots_kernel(const float* __restrict__ x, const int* __restrict__ ei,
                            float* __restrict__ dots)
{
    int idx = blockIdx.x * 256 + threadIdx.x;
    int e = idx >> 8, t = idx & 255;
    if (e >= NEDGES) return;
    const float* ps = x + (size_t)ei[e] * ND;
    const float* pd = x + (size_t)ei[NEDGES + e] * ND;
    float v;
    if (t < 128) {
        int u = 128 + t * 3;
        v = (ps[u] * pd[u] + ps[u + 1] * pd[u + 1] + ps[u + 2] * pd[u + 2]) * CK1;
    } else {
        int u = 512 + (t - 128) * 5;
        v = (ps[u] * pd[u] + ps[u + 1] * pd[u + 1] + ps[u + 2] * pd[u + 2]
             + ps[u + 3] * pd[u + 3] + ps[u + 4] * pd[u + 4]) * CK2;
    }
    dots[idx] = v;
}

// ============================================================================
// f0 = [s, ||v1||_c, ||v2||_c] from PLANE layout (node side), SPLIT output
// ============================================================================
__global__ void f0_kernel(const float* __restrict__ in,
                          ushort* __restrict__ f0H, ushort* __restrict__ f0L, int M)
{
    int idx = blockIdx.x * 256 + threadIdx.x;
    int r = idx / 384, t = idx - r * 384;
    if (r >= M) return;
    size_t P = (size_t)M * 128;
    const float* p = in + (size_t)r * 128;
    float v;
    if (t < 128) v = p[t];
    else if (t < 256) {
        int u = t - 128;
        float x1 = p[P + u], x2 = p[2 * P + u], x3 = p[3 * P + u];
        v = sqrtf(x1 * x1 + x2 * x2 + x3 * x3);
    } else {
        int u = t - 256;
        float x1 = p[4 * P + u], x2 = p[5 * P + u], x3 = p[6 * P + u],
              x4 = p[7 * P + u], x5 = p[8 * P + u];
        v = sqrtf(x1 * x1 + x2 * x2 + x3 * x3 + x4 * x4 + x5 * x5);
    }
    ushort h = f2bf(v);
    f0H[(size_t)r * 384 + t] = h;
    f0L[(size_t)r * 384 + t] = f2bf(v - bf2f(h));
}

// gate in place on PLANE layout (node side). grid: (ceil(M*128/256), 9)
__global__ void gate_kernel(float* __restrict__ xp, const float* __restrict__ g, int M)
{
    int t = blockIdx.x * 256 + threadIdx.x;
    if (t >= M * 128) return;
    int z = blockIdx.y;
    int r = t >> 7, u = t & 127;
    float* p = xp + (size_t)z * M * 128 + t;
    const float* gr = g + (size_t)r * 384;
    if (z == 0)      *p = gr[u];
    else if (z < 4)  *p *= gr[128 + u];
    else             *p *= gr[256 + u];
}

// ============================================================================
// Wigner TP, plane layout in (xp) and out (fij). 2 edges per block.
// Emits f0 = [o_s, ||o1||, ||o2||] directly, SPLIT bf16.
// ============================================================================
__global__ __launch_bounds__(256) void tp_kernel(
    const float* __restrict__ xp, const int* __restrict__ ei,
    const float* __restrict__ tpw, float* __restrict__ fij,
    ushort* __restrict__ f0H, ushort* __restrict__ f0L, int e0, int ec)
{
    int le = blockIdx.x * 2 + (threadIdx.x >> 7);
    int u = threadIdx.x & 127;
    if (le >= ec) return;
    int e = e0 + le;
    const size_t NP = (size_t)NNODES * 128;
    const float* ps = xp + (size_t)ei[e] * 128 + u;
    const float* pd = xp + (size_t)ei[NEDGES + e] * 128 + u;

    float ss = ps[0], sd = pd[0];
    float a0 = ps[NP],     a1 = ps[2 * NP], a2 = ps[3 * NP];
    float b0 = pd[NP],     b1 = pd[2 * NP], b2 = pd[3 * NP];
    float c0 = ps[4 * NP], c1 = ps[5 * NP], c2 = ps[6 * NP],
          c3 = ps[7 * NP], c4 = ps[8 * NP];
    float d0 = pd[4 * NP], d1 = pd[5 * NP], d2 = pd[6 * NP],
          d3 = pd[7 * NP], d4 = pd[8 * NP];

    const float* w = tpw + (size_t)le * WNW + u;
    float w0 = w[0],    w1 = w[128],  w2 = w[256],  w3 = w[384],  w4 = w[512];
    float w5 = w[640],  w6 = w[768],  w7 = w[896],  w8 = w[1024], w9 = w[1152];
    float w10 = w[1280];

    float dab = a0 * b0 + a1 * b1 + a2 * b2;
    float dcd = c0 * d0 + c1 * d1 + c2 * d2 + c3 * d3 + c4 * d4;

    float o_s = PW0 * (w0 * ss * sd + w4 * CK1 * dab + w9 * CK2 * dcd);

    float R0 = A0A * a0 * d2 + A2C * (a1 * d1 + a2 * d0 - a0 * d4);
    float R1 = A0B * a1 * d2 + A2C * (a0 * d1 + a2 * d3);
    float R2 = A0A * a2 * d2 + A2C * (a1 * d3 + a0 * d0 + a2 * d4);
    float U0 = A0A * b0 * c2 + A2C * (b1 * c1 + b2 * c0 - b0 * c4);
    float U1 = A0B * b1 * c2 + A2C * (b0 * c1 + b2 * c3);
    float U2 = A0A * b2 * c2 + A2C * (b1 * c3 + b0 * c0 + b2 * c4);
    float o1_0 = PW1 * (CK1 * (w1 * ss * b0 + w3 * a0 * sd) + w6 * R0 + w8 * U0);
    float o1_1 = PW1 * (CK1 * (w1 * ss * b1 + w3 * a1 * sd) + w6 * R1 + w8 * U1);
    float o1_2 = PW1 * (CK1 * (w1 * ss * b2 + w3 * a2 * sd) + w6 * R2 + w8 * U2);

    float S0 = A2C * (a0 * b2 + a2 * b0);
    float S1 = A2C * (a0 * b1 + a1 * b0);
    float S2 = A0A * (a0 * b0 + a2 * b2) + A0B * a1 * b1;
    float S3 = A2C * (a1 * b2 + a2 * b1);
    float S4 = A2C * (a2 * b2 - a0 * b0);
    float V0 = -B2C * (c0 * d2 + c2 * d0) + B3C * (c1 * d3 + c3 * d1);
    float V1 =  B3C * (c0 * d3 + c3 * d0) - B3C * (c1 * d4 + c4 * d1)
              + B1C * (c1 * d2 + c2 * d1);
    float V2 = -B2C * (c0 * d0 + c4 * d4) + B1C * (c1 * d1 + c3 * d3) + B2C * c2 * d2;
    float V3 =  B3C * (c0 * d1 + c1 * d0) + B3C * (c3 * d4 + c4 * d3)
              + B1C * (c2 * d3 + c3 * d2);
    float V4 = -B2C * (c2 * d4 + c4 * d2) - B3C * c1 * d1 + B3C * c3 * d3;
    float o2_0 = PW2 * (CK2 * (w2 * ss * d0 + w7 * c0 * sd) + w5 * S0 + w10 * V0);
    float o2_1 = PW2 * (CK2 * (w2 * ss * d1 + w7 * c1 * sd) + w5 * S1 + w10 * V1);
    float o2_2 = PW2 * (CK2 * (w2 * ss * d2 + w7 * c2 * sd) + w5 * S2 + w10 * V2);
    float o2_3 = PW2 * (CK2 * (w2 * ss * d3 + w7 * c3 * sd) + w5 * S3 + w10 * V3);
    float o2_4 = PW2 * (CK2 * (w2 * ss * d4 + w7 * c4 * sd) + w5 * S4 + w10 * V4);

    size_t FP = (size_t)ec * 128;
    float* po = fij + (size_t)le * 128 + u;
    po[0] = o_s;
    po[FP] = o1_0;     po[2 * FP] = o1_1; po[3 * FP] = o1_2;
    po[4 * FP] = o2_0; po[5 * FP] = o2_1; po[6 * FP] = o2_2;
    po[7 * FP] = o2_3; po[8 * FP] = o2_4;

    // fused f0 = [s, ||v1||, ||v2||], split bf16 at producer
    float n1 = sqrtf(o1_0 * o1_0 + o1_1 * o1_1 + o1_2 * o1_2);
    float n2 = sqrtf(o2_0 * o2_0 + o2_1 * o2_1 + o2_2 * o2_2
                     + o2_3 * o2_3 + o2_4 * o2_4);
    size_t fb = (size_t)le * 384;
    ushort h;
    h = f2bf(o_s); f0H[fb + u]       = h; f0L[fb + u]       = f2bf(o_s - bf2f(h));
    h = f2bf(n1);  f0H[fb + 128 + u] = h; f0L[fb + 128 + u] = f2bf(n1 - bf2f(h));
    h = f2bf(n2);  f0H[fb + 256 + u] = h; f0L[fb + 256 + u] = f2bf(n2 - bf2f(h));
}

// ============================================================================
extern "C" void kernel_launch(void* const* d_in, const int* in_sizes, int n_in,
                              void* d_out, int out_size, void* d_ws, size_t ws_size,
                              hipStream_t stream)
{
    const float* x         = (const float*)d_in[0];
    const float* edge_attr = (const float*)d_in[1];
    const int*   ei        = (const int*)  d_in[2];
    const float* W_pre0    = (const float*)d_in[3];
    const float* W_pre1    = (const float*)d_in[4];
    const float* W_pre2    = (const float*)d_in[5];
    const float* b_pre0    = (const float*)d_in[6];
    const float* ngpre_W1  = (const float*)d_in[7];
    const float* ngpre_b1  = (const float*)d_in[8];
    const float* ngpre_W2  = (const float*)d_in[9];
    const float* ngpre_b2  = (const float*)d_in[10];
    const float* es_W1     = (const float*)d_in[11];
    const float* es_b1     = (const float*)d_in[12];
    const float* es_W2     = (const float*)d_in[13];
    const float* es_b2     = (const float*)d_in[14];
    const float* er_W1     = (const float*)d_in[15];
    const float* er_b1     = (const float*)d_in[16];
    const float* er_W2     = (const float*)d_in[17];
    const float* er_b2     = (const float*)d_in[18];
    const float* ngpost_W1 = (const float*)d_in[19];
    const float* ngpost_b1 = (const float*)d_in[20];
    const float* ngpost_W2 = (const float*)d_in[21];
    const float* ngpost_b2 = (const float*)d_in[22];
    const float* W_post0   = (const float*)d_in[23];
    const float* W_post1   = (const float*)d_in[24];
    const float* W_post2   = (const float*)d_in[25];
    float* out = (float*)d_out;
    float* ws  = (float*)d_ws;

    // fixed workspace layout:
    //   xp planes  : 11,520,000 fl
    //   hes/her H/L: 4 x 6,400,000 ushort (= 12.8M fl)
    //   wsp        : 2,236,416 ushort weight-split arena
    float* xp    = ws;
    ushort* hesH = (ushort*)ws + 23040000;
    ushort* hesL = hesH + 6400000;
    ushort* herH = hesL + 6400000;
    ushort* herL = herH + 6400000;
    ushort* wsp  = herL + 6400000;                 // ushort offset 48,640,000
    const ushort* esW2H  = wsp;
    const ushort* esW2L  = wsp + 180224;
    const ushort* erW2H  = wsp + 360448;
    const ushort* erW2L  = wsp + 540672;
    const ushort* preW1H = wsp + 720896;
    const ushort* preW1L = wsp + 868352;
    const ushort* preW2H = wsp + 1015808;
    const ushort* preW2L = wsp + 1163264;
    const ushort* postW1H = wsp + 1310720;
    const ushort* postW1L = wsp + 1458176;
    const ushort* postW2H = wsp + 1605632;
    const ushort* postW2L = wsp + 1753088;
    const ushort* o3pW0H = wsp + 1900544;
    const ushort* o3pW0L = wsp + 1916928;
    const ushort* o3pW1H = wsp + 1933312;
    const ushort* o3pW1L = wsp + 1949696;
    const ushort* o3pW2H = wsp + 1966080;
    const ushort* o3pW2L = wsp + 1982464;
    const ushort* preL0H = wsp + 1998848;   // W_pre0
    const ushort* preL0L = wsp + 2015232;
    const ushort* preL1H = wsp + 2031616;   // W_pre1
    const ushort* preL1L = wsp + 2048000;
    const ushort* preL2H = wsp + 2064384;   // W_pre2
    const ushort* preL2L = wsp + 2080768;
    const ushort* esW1H  = wsp + 2097152;
    const ushort* esW1L  = wsp + 2162688;
    const ushort* erW1H  = wsp + 2228224;
    const ushort* erW1L  = wsp + 2232320;   // end 2,236,416 ush
    float* arena = ws + 25438208;           // fixed 25.44M floats

    long ws_floats = (long)(ws_size / 4);
    long arena_f = ws_floats - 25438208L;
    long ec0 = arena_f / 2944;              // tpw(1408)+fij(1152)+f0split(384) per edge
    if (ec0 > NEDGES) ec0 = NEDGES;
    if (ec0 < 1) ec0 = 1;
    int NC = (int)((NEDGES + ec0 - 1) / ec0);
    int Ec = (NEDGES + NC - 1) / NC;

    float* dots = arena;                    // pre-loop use only

    // ---- one-time weight split/transpose ----
    wsplit_kernel<<<dim3(704, 14), 256, 0, stream>>>(
        es_W2, er_W2, ngpre_W1, ngpre_W2, ngpost_W1, ngpost_W2,
        W_post0, W_post1, W_post2, W_pre0, W_pre1, W_pre2,
        es_W1, er_W1, wsp);

    // ---- edge hidden MLPs (full E), MFMA, split output ----
    dots_kernel<<<NEDGES, 256, 0, stream>>>(x, ei, dots);

    dim3 gE(1, (NEDGES + 127) / 128);
    gemmbf<0, 1, 2, 1><<<gE, 256, 0, stream>>>(
        nullptr, nullptr, 0, esW1H, esW1L, es_b1,
        nullptr, nullptr, nullptr, nullptr, nullptr, nullptr, nullptr,
        nullptr, hesH, hesL, 128, NEDGES, 512, 512, x, ei, dots);
    gemmbf<0, 1, 0, 1><<<gE, 256, 0, stream>>>(
        edge_attr, nullptr, EDIM, erW1H, erW1L, er_b1,
        nullptr, nullptr, nullptr, nullptr, nullptr, nullptr, nullptr,
        nullptr, herH, herL, 128, NEDGES, 32, EDIM, nullptr, nullptr, nullptr);

    // ---- node pre: xp = o3_linear(x) planes, MFMA ----
    dim3 gO3p(1, (NNODES + 127) / 128, 9);
    gemmbf<0, 0, 3, 2><<<gO3p, 256, 0, stream>>>(
        x, nullptr, ND, preL0H, preL0L, b_pre0,
        nullptr, nullptr, preL1H, preL1L, nullptr, preL2H, preL2L,
        xp, nullptr, nullptr, 128, NNODES, 128, 128, nullptr, nullptr, nullptr);

    // ---- node norm-gate ----
    ushort* f0nH = (ushort*)arena;
    ushort* f0nL = f0nH + (size_t)NNODES * 384;
    ushort* hbH  = f0nL + (size_t)NNODES * 384;
    ushort* hbL  = hbH + (size_t)NNODES * 384;
    float*  gb   = arena + (size_t)NNODES * 384 * 2;   // after the 4 ushort arrays
    f0_kernel<<<((size_t)NNODES * 384 + 255) / 256, 256, 0, stream>>>(xp, f0nH, f0nL, NNODES);
    dim3 gNGp(3, (NNODES + 127) / 128);
    gemmbf<0, 1, 1, 1><<<gNGp, 256, 0, stream>>>(
        f0nH, f0nL, 384, preW1H, preW1L, ngpre_b1,
        nullptr, nullptr, nullptr, nullptr, nullptr, nullptr, nullptr,
        nullptr, hbH, hbL, 384, NNODES, 384, 384, nullptr, nullptr, nullptr);
    gemmbf<0, 0, 1, 0><<<gNGp, 256, 0, stream>>>(
        hbH, hbL, 384, preW2H, preW2L, ngpre_b2,
        nullptr, nullptr, nullptr, nullptr, nullptr, nullptr, nullptr,
        gb, nullptr, nullptr, 384, NNODES, 384, 384, nullptr, nullptr, nullptr);
    dim3 gGp((NNODES * 128 + 255) / 256, 9);
    gate_kernel<<<gGp, 256, 0, stream>>>(xp, gb, NNODES);

    // ---- edge chunks ----
    for (int c = 0; c < NC; ++c) {
        int e0 = c * Ec;
        int ec = NEDGES - e0; if (ec > Ec) ec = Ec;
        if (ec <= 0) break;

        float* tpwc  = arena;
        float* fijc  = tpwc + (size_t)Ec * 1408;
        ushort* f0pH = (ushort*)(fijc + (size_t)Ec * 1152);
        ushort* f0pL = f0pH + (size_t)Ec * 384;

        // fused DUAL MFMA: tpw = (hes@es_W2 + es_b2) * (her@er_W2 + er_b2)
        dim3 gW(11, (ec + 127) / 128);
        gemmbf<1, 0, 1, 0><<<gW, 256, 0, stream>>>(
            hesH + (size_t)e0 * 128, hesL + (size_t)e0 * 128, 128,
            esW2H, esW2L, es_b2,
            herH + (size_t)e0 * 128, herL + (size_t)e0 * 128,
            erW2H, erW2L, er_b2, nullptr, nullptr,
            tpwc, nullptr, nullptr, WNW, ec, 128, 128, nullptr, nullptr, nullptr);

        // TP + fused split f0
        tp_kernel<<<(ec + 1) / 2, 256, 0, stream>>>(xp, ei, tpwc, fijc, f0pH, f0pL, e0, ec);

        // tpw dead: reuse its slot for h1 (split) + g (fp32)
        ushort* h1H = (ushort*)tpwc;
        ushort* h1L = h1H + (size_t)Ec * 384;
        float*  gp  = tpwc + (size_t)Ec * 384;     // after h1's Ec*384 fl-equiv
        dim3 gNG(3, (ec + 127) / 128);
        gemmbf<0, 1, 1, 1><<<gNG, 256, 0, stream>>>(
            f0pH, f0pL, 384, postW1H, postW1L, ngpost_b1,
            nullptr, nullptr, nullptr, nullptr, nullptr, nullptr, nullptr,
            nullptr, h1H, h1L, 384, ec, 384, 384, nullptr, nullptr, nullptr);
        gemmbf<0, 0, 1, 0><<<gNG, 256, 0, stream>>>(
            h1H, h1L, 384, postW2H, postW2L, ngpost_b2,
            nullptr, nullptr, nullptr, nullptr, nullptr, nullptr, nullptr,
            gp, nullptr, nullptr, 384, ec, 384, 384, nullptr, nullptr, nullptr);

        // o3-post: multi-plane MFMA, gate fused, contiguous interleaved writes
        size_t FPc = (size_t)ec * 128;
        int nb = (ec + 31) / 32;
        o3postbf<1, 0, 0><<<nb, 256, 0, stream>>>(
            nullptr, 0, gp, o3pW0H, o3pW0L, out + (size_t)e0 * ND, ec);
        o3postbf<3, 128, 128><<<nb, 256, 0, stream>>>(
            fijc + FPc, FPc, gp, o3pW1H, o3pW1L, out + (size_t)e0 * ND, ec);
        o3postbf<5, 512, 256><<<nb, 256, 0, stream>>>(
            fijc + 4 * FPc, FPc, gp, o3pW2H, o3pW2L, out + (size_t)e0 * ND, ec);
    }
}

// Round 5
// 1386.245 us; speedup vs baseline: 1.0723x; 1.0723x over previous
//
#include <hip/hip_runtime.h>
#include <math.h>

#define NNODES 10000
#define NEDGES 50000
#define ND 1152
#define MUL 128
#define WNW 1408
#define EDIM 20

#define CK1 0.5773502691896258f
#define CK2 0.4472135954999579f
#define A2C 0.31622776601683794f
#define A0A (-0.18257418583505536f)
#define A0B 0.3651483716701107f
#define B1C 0.11952286093343936f
#define B2C 0.23904572186687873f
#define B3C 0.20701966780270626f
#define PW0 0.5773502691896258f
#define PW1 0.8660254037844386f
#define PW2 1.1180339887498949f
#define INV128 0.08838834764831845f

__device__ __forceinline__ float silu_f(float v) { return v / (1.f + expf(-v)); }

typedef short bfrag __attribute__((ext_vector_type(8)));   // 8 bf16 (4 VGPR)
typedef float f32x4 __attribute__((ext_vector_type(4)));

__device__ __forceinline__ ushort f2bf(float f) {          // RNE fp32->bf16
    uint u = __float_as_uint(f);
    u += 0x7fffu + ((u >> 16) & 1u);
    return (ushort)(u >> 16);
}
__device__ __forceinline__ float bf2f(ushort h) {
    return __uint_as_float(((uint)h) << 16);
}

// async global->LDS, 16B per lane (global_load_lds_dwordx4)
__device__ __forceinline__ void gload16(const void* g, void* l) {
    __builtin_amdgcn_global_load_lds(
        (const __attribute__((address_space(1))) void*)g,
        (__attribute__((address_space(3))) void*)l, 16, 0, 0);
}

#define LSTR 40   // LDS row stride in bf16 for o3postbf (80 B -> <=2-way)

// ============================================================================
// Unified split-bf16 MFMA GEMM.  C = A @ B (+bias variants).
// LDS tiles: linear [128][32] bf16 (8 KB each, 32 KB total), XOR-swizzled at
// 8-B cell granularity with even-only XOR: cell' = cell ^ (row&6).
//  - keeps every 16-B transfer contiguous & 16-B aligned
//  - read banks per quarter-wave: {0,16,4,20,8,24,12,28} -> 2-way (free)
// Staged via global_load_lds (pre-split A/B) with the swizzle applied on the
// per-lane GLOBAL source address (LDS write linear); reg-staged paths write
// ds at the same swizzled offsets. Reads apply the identical XOR.
// A sources (ASRC): 0 fp32 guarded Kreal; 1 pre-split H/L (gload_lds when the
// row-block is full, guarded reg path otherwise); 2 s0 gather; 3 o3pre strided.
// OSINK: 0 fp32 (+SILU); 1 split H/L (+SILU); 2 o3pre plane (*INV128,+b@z0).
// DUAL: C = (r1+b1)*(r2+b2).
// ============================================================================
template<int DUAL, int SILU, int ASRC, int OSINK>
__global__ __launch_bounds__(256) void gemmbf(
    const void* __restrict__ A1p, const void* __restrict__ A1s, int lda,
    const ushort* __restrict__ B1H, const ushort* __restrict__ B1L,
    const float* __restrict__ b1,
    const void* __restrict__ A2p, const void* __restrict__ A2s,
    const ushort* __restrict__ B2H, const ushort* __restrict__ B2L,
    const float* __restrict__ b2,
    const ushort* __restrict__ W2H, const ushort* __restrict__ W2L,
    float* __restrict__ C, ushort* __restrict__ CH, ushort* __restrict__ CL,
    int ldc, int M, int K, int Kreal,
    const float* __restrict__ xg, const int* __restrict__ ei,
    const float* __restrict__ dots)
{
    __shared__ __align__(16) ushort Ah[4096];
    __shared__ __align__(16) ushort Al[4096];
    __shared__ __align__(16) ushort Bh[4096];
    __shared__ __align__(16) ushort Bl[4096];

    const int tid = threadIdx.x;
    const int l   = tid & 63;
    const int wid = tid >> 6;
    const int wr  = (wid >> 1) << 6;       // wave row offset (0/64)
    const int wc  = (wid & 1) << 6;        // wave col offset (0/64)
    const int rowBase = blockIdx.y << 7;
    const int n0      = blockIdx.x << 7;
    const bool fullA  = (ASRC == 1) && (rowBase + 128 <= M);

    // gload slot mapping: slot s covers LDS 16B [s*16, s*16+16); row=s>>2, j=s&3
    const int gr0 = tid >> 2;              // rows 0..63 (slot tid)
    const int gj  = tid & 3;
    const int gsw = ((2 * gj) ^ (gr0 & 6)) << 2;   // swizzled src col (ushorts);
                                                   // (row+64)&6 == row&6 -> same
    const int ld0 = tid * 8;               // LDS ushort offset slot tid
    const int ld1 = (tid + 256) * 8;       // slot tid+256 (rows 64..127)

    // reg-path A staging mapping (thread covers row sRow, bf16 [sK16, sK16+16))
    const int sRow = tid >> 1;
    const int sK16 = (tid & 1) << 4;
    const int wj0  = sK16 >> 3;            // chunk 0 or 2
    const int wd0  = sRow * 32 + (((2 * wj0) ^ (sRow & 6)) << 2);
    const int wd1  = sRow * 32 + (((2 * (wj0 + 1)) ^ (sRow & 6)) << 2);

    // fragment read offsets (ushorts), 16-B aligned by even^even XOR
    const int frow = l & 15;
    const int fk   = (l >> 4) << 3;        // 0,8,16,24 bf16
    int aoff[4], boff[4];
#pragma unroll
    for (int m = 0; m < 4; ++m) {
        int r = wr + m * 16 + frow;
        aoff[m] = r * 32 + ((((fk >> 2)) ^ (r & 6)) << 2);
    }
#pragma unroll
    for (int n = 0; n < 4; ++n) {
        int r = wc + n * 16 + frow;
        boff[n] = r * 32 + ((((fk >> 2)) ^ (r & 6)) << 2);
    }

    // o3pre per-z config
    const int z = (ASRC == 3) ? blockIdx.z : 0;
    int zoff = 0, zstride = 1;
    if constexpr (ASRC == 3) {
        if (z == 0)      { zoff = 0;             zstride = 1; }
        else if (z < 4)  { zoff = 128 + (z - 1); zstride = 3; }
        else             { zoff = 512 + (z - 4); zstride = 5; }
    }

    f32x4 acc0[4][4], acc1[4][4];
#pragma unroll
    for (int m = 0; m < 4; ++m)
#pragma unroll
        for (int n = 0; n < 4; ++n) {
            acc0[m][n] = f32x4{0.f, 0.f, 0.f, 0.f};
            if constexpr (DUAL) acc1[m][n] = f32x4{0.f, 0.f, 0.f, 0.f};
        }

#pragma unroll
    for (int ph = 0; ph < (DUAL ? 2 : 1); ++ph) {
        const void* Ap  = (DUAL && ph) ? A2p : A1p;
        const void* Asp = (DUAL && ph) ? A2s : A1s;
        const ushort* BH = (DUAL && ph) ? B2H : B1H;
        const ushort* BL = (DUAL && ph) ? B2L : B1L;
        if constexpr (ASRC == 3) {        // o3 weight select by l
            if (z >= 1 && z < 4) { BH = B2H; BL = B2L; }
            else if (z >= 4)     { BH = W2H; BL = W2L; }
        }

        // per-lane swizzled source bases (k0 added in-loop)
        const ushort* bh0 = BH + (size_t)(n0 + gr0) * K + gsw;
        const ushort* bh1 = BH + (size_t)(n0 + gr0 + 64) * K + gsw;
        const ushort* bl0 = BL + (size_t)(n0 + gr0) * K + gsw;
        const ushort* bl1 = BL + (size_t)(n0 + gr0 + 64) * K + gsw;
        const ushort* ah0 = nullptr; const ushort* ah1 = nullptr;
        const ushort* al0 = nullptr; const ushort* al1 = nullptr;
        if constexpr (ASRC == 1) {
            ah0 = (const ushort*)Ap  + (size_t)(rowBase + gr0) * lda + gsw;
            ah1 = (const ushort*)Ap  + (size_t)(rowBase + gr0 + 64) * lda + gsw;
            al0 = (const ushort*)Asp + (size_t)(rowBase + gr0) * lda + gsw;
            al1 = (const ushort*)Asp + (size_t)(rowBase + gr0 + 64) * lda + gsw;
        }

        for (int k0 = 0; k0 < K; k0 += 32) {
            // ---- stage B: async DMA, swizzled source ----
            gload16(bh0 + k0, &Bh[ld0]);
            gload16(bh1 + k0, &Bh[ld1]);
            gload16(bl0 + k0, &Bl[ld0]);
            gload16(bl1 + k0, &Bl[ld1]);
            // ---- stage A ----
            if (fullA) {
                gload16(ah0 + k0, &Ah[ld0]);
                gload16(ah1 + k0, &Ah[ld1]);
                gload16(al0 + k0, &Al[ld0]);
                gload16(al1 + k0, &Al[ld1]);
            } else if constexpr (ASRC == 1) {
                // guarded tail block: pre-split loads, swizzled ds_write
                int grow = rowBase + sRow;
                uint4 H0 = {0,0,0,0}, H1 = {0,0,0,0};
                uint4 L0 = {0,0,0,0}, L1 = {0,0,0,0};
                if (grow < M) {
                    const ushort* AH = (const ushort*)Ap  + (size_t)grow * lda + k0 + sK16;
                    const ushort* AL = (const ushort*)Asp + (size_t)grow * lda + k0 + sK16;
                    H0 = *(const uint4*)AH; H1 = *(const uint4*)(AH + 8);
                    L0 = *(const uint4*)AL; L1 = *(const uint4*)(AL + 8);
                }
                *(uint4*)&Ah[wd0] = H0; *(uint4*)&Ah[wd1] = H1;
                *(uint4*)&Al[wd0] = L0; *(uint4*)&Al[wd1] = L1;
            } else {
                // fp32 / gather / strided: load 16 floats, split, swizzled write
                float f[16];
                int grow = rowBase + sRow;
                if (grow < M) {
                    if constexpr (ASRC == 0) {
#pragma unroll
                        for (int j = 0; j < 16; ++j) {
                            int gk = k0 + sK16 + j;
                            f[j] = (gk < Kreal)
                                 ? ((const float*)Ap)[(size_t)grow * lda + gk] : 0.f;
                        }
                    } else if constexpr (ASRC == 2) {
                        int gk = k0 + sK16;
                        const float4* p;
                        if (gk < 128)
                            p = (const float4*)&xg[(size_t)ei[grow] * ND + gk];
                        else if (gk < 256)
                            p = (const float4*)&xg[(size_t)ei[NEDGES + grow] * ND + (gk - 128)];
                        else
                            p = (const float4*)&dots[(size_t)grow * 256 + (gk - 256)];
#pragma unroll
                        for (int j = 0; j < 4; ++j) {
                            float4 v = p[j];
                            f[j*4+0] = v.x; f[j*4+1] = v.y;
                            f[j*4+2] = v.z; f[j*4+3] = v.w;
                        }
                    } else {  // ASRC == 3
                        const float* p = &((const float*)Ap)[(size_t)grow * lda + zoff];
#pragma unroll
                        for (int j = 0; j < 16; ++j)
                            f[j] = p[(k0 + sK16 + j) * zstride];
                    }
                } else {
#pragma unroll
                    for (int j = 0; j < 16; ++j) f[j] = 0.f;
                }
                uint hw[8], lw[8];
#pragma unroll
                for (int jj = 0; jj < 8; ++jj) {
                    ushort ha = f2bf(f[2*jj]),   hb = f2bf(f[2*jj+1]);
                    ushort la = f2bf(f[2*jj]   - bf2f(ha));
                    ushort lb = f2bf(f[2*jj+1] - bf2f(hb));
                    hw[jj] = (uint)ha | ((uint)hb << 16);
                    lw[jj] = (uint)la | ((uint)lb << 16);
                }
                uint4 H0 = {hw[0], hw[1], hw[2], hw[3]};
                uint4 H1 = {hw[4], hw[5], hw[6], hw[7]};
                uint4 L0 = {lw[0], lw[1], lw[2], lw[3]};
                uint4 L1 = {lw[4], lw[5], lw[6], lw[7]};
                *(uint4*)&Ah[wd0] = H0; *(uint4*)&Ah[wd1] = H1;
                *(uint4*)&Al[wd0] = L0; *(uint4*)&Al[wd1] = L1;
            }
            __syncthreads();
            // ---- fragments + MFMA (3 split products) ----
            bfrag bhF[4], blF[4];
#pragma unroll
            for (int n = 0; n < 4; ++n) {
                bhF[n] = *(const bfrag*)&Bh[boff[n]];
                blF[n] = *(const bfrag*)&Bl[boff[n]];
            }
#pragma unroll
            for (int m = 0; m < 4; ++m) {
                bfrag ah = *(const bfrag*)&Ah[aoff[m]];
                bfrag al = *(const bfrag*)&Al[aoff[m]];
#pragma unroll
                for (int n = 0; n < 4; ++n) {
                    f32x4 a = (DUAL && ph) ? acc1[m][n] : acc0[m][n];
                    a = __builtin_amdgcn_mfma_f32_16x16x32_bf16(ah, bhF[n], a, 0, 0, 0);
                    a = __builtin_amdgcn_mfma_f32_16x16x32_bf16(ah, blF[n], a, 0, 0, 0);
                    a = __builtin_amdgcn_mfma_f32_16x16x32_bf16(al, bhF[n], a, 0, 0, 0);
                    if (DUAL && ph) acc1[m][n] = a; else acc0[m][n] = a;
                }
            }
            __syncthreads();
        }
    }

    // ---- epilogue ----
#pragma unroll
    for (int n = 0; n < 4; ++n) {
        int col = n0 + wc + n * 16 + frow;
        float bb1 = b1 ? b1[col] : 0.f;
        float bb2 = (DUAL && b2) ? b2[col] : 0.f;
#pragma unroll
        for (int m = 0; m < 4; ++m) {
            int row0 = rowBase + wr + m * 16 + ((l >> 4) << 2);
#pragma unroll
            for (int q = 0; q < 4; ++q) {
                int row = row0 + q;
                if (row >= M) continue;
                if constexpr (DUAL) {
                    float v = (acc0[m][n][q] + bb1) * (acc1[m][n][q] + bb2);
                    C[(size_t)row * ldc + col] = v;
                } else if constexpr (OSINK == 0) {
                    float v = acc0[m][n][q] + bb1;
                    if constexpr (SILU) v = silu_f(v);
                    C[(size_t)row * ldc + col] = v;
                } else if constexpr (OSINK == 1) {
                    float v = acc0[m][n][q] + bb1;
                    if constexpr (SILU) v = silu_f(v);
                    ushort h  = f2bf(v);
                    ushort lo = f2bf(v - bf2f(h));
                    CH[(size_t)row * ldc + col] = h;
                    CL[(size_t)row * ldc + col] = lo;
                } else {  // OSINK == 2 : o3pre plane
                    float v = acc0[m][n][q] * INV128;
                    if (z == 0 && b1) v += b1[col];
                    C[(size_t)z * M * ldc + (size_t)row * ldc + col] = v;
                }
            }
        }
    }
}

// ============================================================================
// o3-post multi-plane split-bf16 MFMA (unchanged):
//   out[row, OFF + col*NPL + p] = INV128 * sum_u (fij_p[row,u]*g[row,GOFF+u]) W[u,col]
// ============================================================================
template<int NPL, int OFF, int GOFF>
__global__ __launch_bounds__(256) void o3postbf(
    const float* __restrict__ fij, size_t FP,
    const float* __restrict__ g,
    const ushort* __restrict__ WH, const ushort* __restrict__ WL,
    float* __restrict__ out, int M)
{
    __shared__ __align__(16) ushort Ah[NPL * 32 * LSTR];
    __shared__ __align__(16) ushort Al[NPL * 32 * LSTR];
    __shared__ __align__(16) ushort Bh[128 * LSTR];
    __shared__ __align__(16) ushort Bl[128 * LSTR];

    const int tid = threadIdx.x;
    const int l   = tid & 63;
    const int wid = tid >> 6;
    const int wr  = (wid >> 1) << 4;
    const int wc  = (wid & 1) << 6;
    const int rowBase = blockIdx.x << 5;

    const int sR = tid >> 3;
    const int sK = (tid & 7) << 2;
    const int bN = tid & 127;
    const int bK = (tid >> 7) << 4;

    const int frow = l & 15;
    const int fk   = (l >> 4) << 3;

    f32x4 acc[NPL][4];
#pragma unroll
    for (int p = 0; p < NPL; ++p)
#pragma unroll
        for (int n = 0; n < 4; ++n) acc[p][n] = f32x4{0.f, 0.f, 0.f, 0.f};

    for (int k0 = 0; k0 < 128; k0 += 32) {
        int grow = rowBase + sR;
        float4 g4 = make_float4(0.f, 0.f, 0.f, 0.f);
        if (grow < M)
            g4 = *(const float4*)&g[(size_t)grow * 384 + GOFF + k0 + sK];
#pragma unroll
        for (int p = 0; p < NPL; ++p) {
            float4 v;
            if constexpr (NPL == 1) {
                v = g4;
            } else {
                float4 f4 = make_float4(0.f, 0.f, 0.f, 0.f);
                if (grow < M)
                    f4 = *(const float4*)&fij[(size_t)p * FP + (size_t)grow * 128 + k0 + sK];
                v = make_float4(f4.x * g4.x, f4.y * g4.y, f4.z * g4.z, f4.w * g4.w);
            }
            ushort4 hv, lv;
            hv.x = f2bf(v.x); lv.x = f2bf(v.x - bf2f(hv.x));
            hv.y = f2bf(v.y); lv.y = f2bf(v.y - bf2f(hv.y));
            hv.z = f2bf(v.z); lv.z = f2bf(v.z - bf2f(hv.z));
            hv.w = f2bf(v.w); lv.w = f2bf(v.w - bf2f(hv.w));
            int base = (p * 32 + sR) * LSTR + sK;
            *(ushort4*)&Ah[base] = hv;
            *(ushort4*)&Al[base] = lv;
        }
        {
            size_t go = (size_t)bN * 128 + k0 + bK;
            uint4 h0 = *(const uint4*)&WH[go];
            uint4 h1 = *(const uint4*)&WH[go + 8];
            uint4 l0 = *(const uint4*)&WL[go];
            uint4 l1 = *(const uint4*)&WL[go + 8];
            int bb = bN * LSTR + bK;
            *(uint4*)&Bh[bb]     = h0;
            *(uint4*)&Bh[bb + 8] = h1;
            *(uint4*)&Bl[bb]     = l0;
            *(uint4*)&Bl[bb + 8] = l1;
        }
        __syncthreads();
        bfrag bhF[4], blF[4];
#pragma unroll
        for (int n = 0; n < 4; ++n) {
            int r = (wc + n * 16 + frow) * LSTR + fk;
            bhF[n] = *(const bfrag*)&Bh[r];
            blF[n] = *(const bfrag*)&Bl[r];
        }
#pragma unroll
        for (int p = 0; p < NPL; ++p) {
            int r = (p * 32 + wr + frow) * LSTR + fk;
            bfrag ah = *(const bfrag*)&Ah[r];
            bfrag al = *(const bfrag*)&Al[r];
#pragma unroll
            for (int n = 0; n < 4; ++n) {
                acc[p][n] = __builtin_amdgcn_mfma_f32_16x16x32_bf16(ah, bhF[n], acc[p][n], 0, 0, 0);
                acc[p][n] = __builtin_amdgcn_mfma_f32_16x16x32_bf16(ah, blF[n], acc[p][n], 0, 0, 0);
                acc[p][n] = __builtin_amdgcn_mfma_f32_16x16x32_bf16(al, bhF[n], acc[p][n], 0, 0, 0);
            }
        }
        __syncthreads();
    }

#pragma unroll
    for (int n = 0; n < 4; ++n) {
        int col = wc + n * 16 + frow;
#pragma unroll
        for (int q = 0; q < 4; ++q) {
            int row = rowBase + wr + ((l >> 4) << 2) + q;
            if (row >= M) continue;
            float* po = &out[(size_t)row * ND + OFF + col * NPL];
#pragma unroll
            for (int p = 0; p < NPL; ++p)
                po[p] = acc[p][n][q] * INV128;
        }
    }
}

// ============================================================================
// One-time weight split+transpose: W[K][N] fp32 -> H/L [N][Kp] bf16 (zero-pad
// k in [K, Kp)). grid.y selects matrix; out is one packed ushort arena.
// ============================================================================
__global__ void wsplit_kernel(
    const float* __restrict__ W0,  const float* __restrict__ W1,
    const float* __restrict__ W2,  const float* __restrict__ W3,
    const float* __restrict__ W4,  const float* __restrict__ W5,
    const float* __restrict__ W6,  const float* __restrict__ W7,
    const float* __restrict__ W8,  const float* __restrict__ W9,
    const float* __restrict__ W10, const float* __restrict__ W11,
    const float* __restrict__ W12, const float* __restrict__ W13,
    ushort* __restrict__ out)
{
    int m = blockIdx.y;
    const float* W; int K, Kp, N; size_t off;
    switch (m) {
        case 0:  W = W0;  K = 128; Kp = 128; N = 1408; off = 0;       break;
        case 1:  W = W1;  K = 128; Kp = 128; N = 1408; off = 360448;  break;
        case 2:  W = W2;  K = 384; Kp = 384; N = 384;  off = 720896;  break;
        case 3:  W = W3;  K = 384; Kp = 384; N = 384;  off = 1015808; break;
        case 4:  W = W4;  K = 384; Kp = 384; N = 384;  off = 1310720; break;
        case 5:  W = W5;  K = 384; Kp = 384; N = 384;  off = 1605632; break;
        case 6:  W = W6;  K = 128; Kp = 128; N = 128;  off = 1900544; break;
        case 7:  W = W7;  K = 128; Kp = 128; N = 128;  off = 1933312; break;
        case 8:  W = W8;  K = 128; Kp = 128; N = 128;  off = 1966080; break;
        case 9:  W = W9;  K = 128; Kp = 128; N = 128;  off = 1998848; break;
        case 10: W = W10; K = 128; Kp = 128; N = 128;  off = 2031616; break;
        case 11: W = W11; K = 128; Kp = 128; N = 128;  off = 2064384; break;
        case 12: W = W12; K = 512; Kp = 512; N = 128;  off = 2097152; break;
        default: W = W13; K = 20;  Kp = 32;  N = 128;  off = 2228224; break;
    }
    int idx = blockIdx.x * 256 + threadIdx.x;
    if (idx >= Kp * N) return;
    int k = idx / N, n = idx - k * N;
    float v = (k < K) ? W[(size_t)k * N + n] : 0.f;
    ushort h  = f2bf(v);
    ushort lo = f2bf(v - bf2f(h));
    size_t KN = (size_t)Kp * N;
    out[off + (size_t)n * Kp + k]      = h;
    out[off + KN + (size_t)n * Kp + k] = lo;
}

// ============================================================================
// dots for s0 (reads interleaved input x)
// ============================================================================
__global__ void dots_kernel(const float* __restrict__ x, const int* __restrict__ ei,
                            float* __restrict__ dots)
{
    int idx = blockIdx.x * 256 + threadIdx.x;
    int e = idx >> 8, t = idx & 255;
    if (e >= NEDGES) return;
    const float* ps = x + (size_t)ei[e] * ND;
    const float* pd = x + (size_t)ei[NEDGES + e] * ND;
    float v;
    if (t < 128) {
        int u = 128 + t * 3;
        v = (ps[u] * pd[u] + ps[u + 1] * pd[u + 1] + ps[u + 2] * pd[u + 2]) * CK1;
    } else {
        int u = 512 + (t - 128) * 5;
        v = (ps[u] * pd[u] + ps[u + 1] * pd[u + 1] + ps[u + 2] * pd[u + 2]
             + ps[u + 3] * pd[u + 3] + ps[u + 4] * pd[u + 4]) * CK2;
    }
    dots[idx] = v;
}

// ============================================================================
// f0 = [s, ||v1||_c, ||v2||_c] from PLANE layout (node side), SPLIT output
// ============================================================================
__global__ void f0_kernel(const float* __restrict__ in,
                          ushort* __restrict__ f0H, ushort* __restrict__ f0L, int M)
{
    int idx = blockIdx.x * 256 + threadIdx.x;
    int r = idx / 384, t = idx - r * 384;
    if (r >= M) return;
    size_t P = (size_t)M * 128;
    const float* p = in + (size_t)r * 128;
    float v;
    if (t < 128) v = p[t];
    else if (t < 256) {
        int u = t - 128;
        float x1 = p[P + u], x2 = p[2 * P + u], x3 = p[3 * P + u];
        v = sqrtf(x1 * x1 + x2 * x2 + x3 * x3);
    } else {
        int u = t - 256;
        float x1 = p[4 * P + u], x2 = p[5 * P + u], x3 = p[6 * P + u],
              x4 = p[7 * P + u], x5 = p[8 * P + u];
        v = sqrtf(x1 * x1 + x2 * x2 + x3 * x3 + x4 * x4 + x5 * x5);
    }
    ushort h = f2bf(v);
    f0H[(size_t)r * 384 + t] = h;
    f0L[(size_t)r * 384 + t] = f2bf(v - bf2f(h));
}

// gate in place on PLANE layout (node side). grid: (ceil(M*128/256), 9)
__global__ void gate_kernel(float* __restrict__ xp, const float* __restrict__ g, int M)
{
    int t = blockIdx.x * 256 + threadIdx.x;
    if (t >= M * 128) return;
    int z = blockIdx.y;
    int r = t >> 7, u = t & 127;
    float* p = xp + (size_t)z * M * 128 + t;
    const float* gr = g + (size_t)r * 384;
    if (z == 0)      *p = gr[u];
    else if (z < 4)  *p *= gr[128 + u];
    else             *p *= gr[256 + u];
}

// ============================================================================
// Wigner TP, plane layout in (xp) and out (fij). 2 edges per block.
// Emits f0 = [o_s, ||o1||, ||o2||] directly, SPLIT bf16.
// ============================================================================
__global__ __launch_bounds__(256) void tp_kernel(
    const float* __restrict__ xp, const int* __restrict__ ei,
    const float* __restrict__ tpw, float* __restrict__ fij,
    ushort* __restrict__ f0H, ushort* __restrict__ f0L, int e0, int ec)
{
    int le = blockIdx.x * 2 + (threadIdx.x >> 7);
    int u = threadIdx.x & 127;
    if (le >= ec) return;
    int e = e0 + le;
    const size_t NP = (size_t)NNODES * 128;
    const float* ps = xp + (size_t)ei[e] * 128 + u;
    const float* pd = xp + (size_t)ei[NEDGES + e] * 128 + u;

    float ss = ps[0], sd = pd[0];
    float a0 = ps[NP],     a1 = ps[2 * NP], a2 = ps[3 * NP];
    float b0 = pd[NP],     b1 = pd[2 * NP], b2 = pd[3 * NP];
    float c0 = ps[4 * NP], c1 = ps[5 * NP], c2 = ps[6 * NP],
          c3 = ps[7 * NP], c4 = ps[8 * NP];
    float d0 = pd[4 * NP], d1 = pd[5 * NP], d2 = pd[6 * NP],
          d3 = pd[7 * NP], d4 = pd[8 * NP];

    const float* w = tpw + (size_t)le * WNW + u;
    float w0 = w[0],    w1 = w[128],  w2 = w[256],  w3 = w[384],  w4 = w[512];
    float w5 = w[640],  w6 = w[768],  w7 = w[896],  w8 = w[1024], w9 = w[1152];
    float w10 = w[1280];

    float dab = a0 * b0 + a1 * b1 + a2 * b2;
    float dcd = c0 * d0 + c1 * d1 + c2 * d2 + c3 * d3 + c4 * d4;

    float o_s = PW0 * (w0 * ss * sd + w4 * CK1 * dab + w9 * CK2 * dcd);

    float R0 = A0A * a0 * d2 + A2C * (a1 * d1 + a2 * d0 - a0 * d4);
    float R1 = A0B * a1 * d2 + A2C * (a0 * d1 + a2 * d3);
    float R2 = A0A * a2 * d2 + A2C * (a1 * d3 + a0 * d0 + a2 * d4);
    float U0 = A0A * b0 * c2 + A2C * (b1 * c1 + b2 * c0 - b0 * c4);
    float U1 = A0B * b1 * c2 + A2C * (b0 * c1 + b2 * c3);
    float U2 = A0A * b2 * c2 + A2C * (b1 * c3 + b0 * c0 + b2 * c4);
    float o1_0 = PW1 * (CK1 * (w1 * ss * b0 + w3 * a0 * sd) + w6 * R0 + w8 * U0);
    float o1_1 = PW1 * (CK1 * (w1 * ss * b1 + w3 * a1 * sd) + w6 * R1 + w8 * U1);
    float o1_2 = PW1 * (CK1 * (w1 * ss * b2 + w3 * a2 * sd) + w6 * R2 + w8 * U2);

    float S0 = A2C * (a0 * b2 + a2 * b0);
    float S1 = A2C * (a0 * b1 + a1 * b0);
    float S2 = A0A * (a0 * b0 + a2 * b2) + A0B * a1 * b1;
    float S3 = A2C * (a1 * b2 + a2 * b1);
    float S4 = A2C * (a2 * b2 - a0 * b0);
    float V0 = -B2C * (c0 * d2 + c2 * d0) + B3C * (c1 * d3 + c3 * d1);
    float V1 =  B3C * (c0 * d3 + c3 * d0) - B3C * (c1 * d4 + c4 * d1)
              + B1C * (c1 * d2 + c2 * d1);
    float V2 = -B2C * (c0 * d0 + c4 * d4) + B1C * (c1 * d1 + c3 * d3) + B2C * c2 * d2;
    float V3 =  B3C * (c0 * d1 + c1 * d0) + B3C * (c3 * d4 + c4 * d3)
              + B1C * (c2 * d3 + c3 * d2);
    float V4 = -B2C * (c2 * d4 + c4 * d2) - B3C * c1 * d1 + B3C * c3 * d3;
    float o2_0 = PW2 * (CK2 * (w2 * ss * d0 + w7 * c0 * sd) + w5 * S0 + w10 * V0);
    float o2_1 = PW2 * (CK2 * (w2 * ss * d1 + w7 * c1 * sd) + w5 * S1 + w10 * V1);
    float o2_2 = PW2 * (CK2 * (w2 * ss * d2 + w7 * c2 * sd) + w5 * S2 + w10 * V2);
    float o2_3 = PW2 * (CK2 * (w2 * ss * d3 + w7 * c3 * sd) + w5 * S3 + w10 * V3);
    float o2_4 = PW2 * (CK2 * (w2 * ss * d4 + w7 * c4 * sd) + w5 * S4 + w10 * V4);

    size_t FP = (size_t)ec * 128;
    float* po = fij + (size_t)le * 128 + u;
    po[0] = o_s;
    po[FP] = o1_0;     po[2 * FP] = o1_1; po[3 * FP] = o1_2;
    po[4 * FP] = o2_0; po[5 * FP] = o2_1; po[6 * FP] = o2_2;
    po[7 * FP] = o2_3; po[8 * FP] = o2_4;

    // fused f0 = [s, ||v1||, ||v2||], split bf16 at producer
    float n1 = sqrtf(o1_0 * o1_0 + o1_1 * o1_1 + o1_2 * o1_2);
    float n2 = sqrtf(o2_0 * o2_0 + o2_1 * o2_1 + o2_2 * o2_2
                     + o2_3 * o2_3 + o2_4 * o2_4);
    size_t fb = (size_t)le * 384;
    ushort h;
    h = f2bf(o_s); f0H[fb + u]       = h; f0L[fb + u]       = f2bf(o_s - bf2f(h));
    h = f2bf(n1);  f0H[fb + 128 + u] = h; f0L[fb + 128 + u] = f2bf(n1 - bf2f(h));
    h = f2bf(n2);  f0H[fb + 256 + u] = h; f0L[fb + 256 + u] = f2bf(n2 - bf2f(h));
}

// ============================================================================
extern "C" void kernel_launch(void* const* d_in, const int* in_sizes, int n_in,
                              void* d_out, int out_size, void* d_ws, size_t ws_size,
                              hipStream_t stream)
{
    const float* x         = (const float*)d_in[0];
    const float* edge_attr = (const float*)d_in[1];
    const int*   ei        = (const int*)  d_in[2];
    const float* W_pre0    = (const float*)d_in[3];
    const float* W_pre1    = (const float*)d_in[4];
    const float* W_pre2    = (const float*)d_in[5];
    const float* b_pre0    = (const float*)d_in[6];
    const float* ngpre_W1  = (const float*)d_in[7];
    const float* ngpre_b1  = (const float*)d_in[8];
    const float* ngpre_W2  = (const float*)d_in[9];
    const float* ngpre_b2  = (const float*)d_in[10];
    const float* es_W1     = (const float*)d_in[11];
    const float* es_b1     = (const float*)d_in[12];
    const float* es_W2     = (const float*)d_in[13];
    const float* es_b2     = (const float*)d_in[14];
    const float* er_W1     = (const float*)d_in[15];
    const float* er_b1     = (const float*)d_in[16];
    const float* er_W2     = (const float*)d_in[17];
    const float* er_b2     = (const float*)d_in[18];
    const float* ngpost_W1 = (const float*)d_in[19];
    const float* ngpost_b1 = (const float*)d_in[20];
    const float* ngpost_W2 = (const float*)d_in[21];
    const float* ngpost_b2 = (const float*)d_in[22];
    const float* W_post0   = (const float*)d_in[23];
    const float* W_post1   = (const float*)d_in[24];
    const float* W_post2   = (const float*)d_in[25];
    float* out = (float*)d_out;
    float* ws  = (float*)d_ws;

    // fixed workspace layout:
    //   xp planes  : 11,520,000 fl
    //   hes/her H/L: 4 x 6,400,000 ushort (= 12.8M fl)
    //   wsp        : 2,236,416 ushort weight-split arena
    float* xp    = ws;
    ushort* hesH = (ushort*)ws + 23040000;
    ushort* hesL = hesH + 6400000;
    ushort* herH = hesL + 6400000;
    ushort* herL = herH + 6400000;
    ushort* wsp  = herL + 6400000;                 // ushort offset 48,640,000
    const ushort* esW2H  = wsp;
    const ushort* esW2L  = wsp + 180224;
    const ushort* erW2H  = wsp + 360448;
    const ushort* erW2L  = wsp + 540672;
    const ushort* preW1H = wsp + 720896;
    const ushort* preW1L = wsp + 868352;
    const ushort* preW2H = wsp + 1015808;
    const ushort* preW2L = wsp + 1163264;
    const ushort* postW1H = wsp + 1310720;
    const ushort* postW1L = wsp + 1458176;
    const ushort* postW2H = wsp + 1605632;
    const ushort* postW2L = wsp + 1753088;
    const ushort* o3pW0H = wsp + 1900544;
    const ushort* o3pW0L = wsp + 1916928;
    const ushort* o3pW1H = wsp + 1933312;
    const ushort* o3pW1L = wsp + 1949696;
    const ushort* o3pW2H = wsp + 1966080;
    const ushort* o3pW2L = wsp + 1982464;
    const ushort* preL0H = wsp + 1998848;   // W_pre0
    const ushort* preL0L = wsp + 2015232;
    const ushort* preL1H = wsp + 2031616;   // W_pre1
    const ushort* preL1L = wsp + 2048000;
    const ushort* preL2H = wsp + 2064384;   // W_pre2
    const ushort* preL2L = wsp + 2080768;
    const ushort* esW1H  = wsp + 2097152;
    const ushort* esW1L  = wsp + 2162688;
    const ushort* erW1H  = wsp + 2228224;
    const ushort* erW1L  = wsp + 2232320;   // end 2,236,416 ush
    float* arena = ws + 25438208;           // fixed 25.44M floats

    long ws_floats = (long)(ws_size / 4);
    long arena_f = ws_floats - 25438208L;
    long ec0 = arena_f / 2944;              // tpw(1408)+fij(1152)+f0split(384) per edge
    if (ec0 > NEDGES) ec0 = NEDGES;
    if (ec0 < 1) ec0 = 1;
    int NC = (int)((NEDGES + ec0 - 1) / ec0);
    int Ec = (NEDGES + NC - 1) / NC;

    float* dots = arena;                    // pre-loop use only

    // ---- one-time weight split/transpose ----
    wsplit_kernel<<<dim3(704, 14), 256, 0, stream>>>(
        es_W2, er_W2, ngpre_W1, ngpre_W2, ngpost_W1, ngpost_W2,
        W_post0, W_post1, W_post2, W_pre0, W_pre1, W_pre2,
        es_W1, er_W1, wsp);

    // ---- edge hidden MLPs (full E), MFMA, split output ----
    dots_kernel<<<NEDGES, 256, 0, stream>>>(x, ei, dots);

    dim3 gE(1, (NEDGES + 127) / 128);
    gemmbf<0, 1, 2, 1><<<gE, 256, 0, stream>>>(
        nullptr, nullptr, 0, esW1H, esW1L, es_b1,
        nullptr, nullptr, nullptr, nullptr, nullptr, nullptr, nullptr,
        nullptr, hesH, hesL, 128, NEDGES, 512, 512, x, ei, dots);
    gemmbf<0, 1, 0, 1><<<gE, 256, 0, stream>>>(
        edge_attr, nullptr, EDIM, erW1H, erW1L, er_b1,
        nullptr, nullptr, nullptr, nullptr, nullptr, nullptr, nullptr,
        nullptr, herH, herL, 128, NEDGES, 32, EDIM, nullptr, nullptr, nullptr);

    // ---- node pre: xp = o3_linear(x) planes, MFMA ----
    dim3 gO3p(1, (NNODES + 127) / 128, 9);
    gemmbf<0, 0, 3, 2><<<gO3p, 256, 0, stream>>>(
        x, nullptr, ND, preL0H, preL0L, b_pre0,
        nullptr, nullptr, preL1H, preL1L, nullptr, preL2H, preL2L,
        xp, nullptr, nullptr, 128, NNODES, 128, 128, nullptr, nullptr, nullptr);

    // ---- node norm-gate ----
    ushort* f0nH = (ushort*)arena;
    ushort* f0nL = f0nH + (size_t)NNODES * 384;
    ushort* hbH  = f0nL + (size_t)NNODES * 384;
    ushort* hbL  = hbH + (size_t)NNODES * 384;
    float*  gb   = arena + (size_t)NNODES * 384 * 2;   // after the 4 ushort arrays
    f0_kernel<<<((size_t)NNODES * 384 + 255) / 256, 256, 0, stream>>>(xp, f0nH, f0nL, NNODES);
    dim3 gNGp(3, (NNODES + 127) / 128);
    gemmbf<0, 1, 1, 1><<<gNGp, 256, 0, stream>>>(
        f0nH, f0nL, 384, preW1H, preW1L, ngpre_b1,
        nullptr, nullptr, nullptr, nullptr, nullptr, nullptr, nullptr,
        nullptr, hbH, hbL, 384, NNODES, 384, 384, nullptr, nullptr, nullptr);
    gemmbf<0, 0, 1, 0><<<gNGp, 256, 0, stream>>>(
        hbH, hbL, 384, preW2H, preW2L, ngpre_b2,
        nullptr, nullptr, nullptr, nullptr, nullptr, nullptr, nullptr,
        gb, nullptr, nullptr, 384, NNODES, 384, 384, nullptr, nullptr, nullptr);
    dim3 gGp((NNODES * 128 + 255) / 256, 9);
    gate_kernel<<<gGp, 256, 0, stream>>>(xp, gb, NNODES);

    // ---- edge chunks ----
    for (int c = 0; c < NC; ++c) {
        int e0 = c * Ec;
        int ec = NEDGES - e0; if (ec > Ec) ec = Ec;
        if (ec <= 0) break;

        float* tpwc  = arena;
        float* fijc  = tpwc + (size_t)Ec * 1408;
        ushort* f0pH = (ushort*)(fijc + (size_t)Ec * 1152);
        ushort* f0pL = f0pH + (size_t)Ec * 384;

        // fused DUAL MFMA: tpw = (hes@es_W2 + es_b2) * (her@er_W2 + er_b2)
        dim3 gW(11, (ec + 127) / 128);
        gemmbf<1, 0, 1, 0><<<gW, 256, 0, stream>>>(
            hesH + (size_t)e0 * 128, hesL + (size_t)e0 * 128, 128,
            esW2H, esW2L, es_b2,
            herH + (size_t)e0 * 128, herL + (size_t)e0 * 128,
            erW2H, erW2L, er_b2, nullptr, nullptr,
            tpwc, nullptr, nullptr, WNW, ec, 128, 128, nullptr, nullptr, nullptr);

        // TP + fused split f0
        tp_kernel<<<(ec + 1) / 2, 256, 0, stream>>>(xp, ei, tpwc, fijc, f0pH, f0pL, e0, ec);

        // tpw dead: reuse its slot for h1 (split) + g (fp32)
        ushort* h1H = (ushort*)tpwc;
        ushort* h1L = h1H + (size_t)Ec * 384;
        float*  gp  = tpwc + (size_t)Ec * 384;     // after h1's Ec*384 fl-equiv
        dim3 gNG(3, (ec + 127) / 128);
        gemmbf<0, 1, 1, 1><<<gNG, 256, 0, stream>>>(
            f0pH, f0pL, 384, postW1H, postW1L, ngpost_b1,
            nullptr, nullptr, nullptr, nullptr, nullptr, nullptr, nullptr,
            nullptr, h1H, h1L, 384, ec, 384, 384, nullptr, nullptr, nullptr);
        gemmbf<0, 0, 1, 0><<<gNG, 256, 0, stream>>>(
            h1H, h1L, 384, postW2H, postW2L, ngpost_b2,
            nullptr, nullptr, nullptr, nullptr, nullptr, nullptr, nullptr,
            gp, nullptr, nullptr, 384, ec, 384, 384, nullptr, nullptr, nullptr);

        // o3-post: multi-plane MFMA, gate fused, contiguous interleaved writes
        size_t FPc = (size_t)ec * 128;
        int nb = (ec + 31) / 32;
        o3postbf<1, 0, 0><<<nb, 256, 0, stream>>>(
            nullptr, 0, gp, o3pW0H, o3pW0L, out + (size_t)e0 * ND, ec);
        o3postbf<3, 128, 128><<<nb, 256, 0, stream>>>(
            fijc + FPc, FPc, gp, o3pW1H, o3pW1L, out + (size_t)e0 * ND, ec);
        o3postbf<5, 512, 256><<<nb, 256, 0, stream>>>(
            fijc + 4 * FPc, FPc, gp, o3pW2H, o3pW2L, out + (size_t)e0 * ND, ec);
    }
}